// Round 1
// baseline (280.852 us; speedup 1.0000x reference)
//
#include <hip/hip_runtime.h>
#include <hip/hip_bf16.h>
#include <stdint.h>

#define BATCH 16384
#define D 1024
#define NCLS 1000
#define NPROTO 5000
#define NPROTO_PAD 5120
#define NTILE_N 40
#define NTILE_M 128

typedef float f32x4 __attribute__((ext_vector_type(4)));
typedef __bf16 bf16x8 __attribute__((ext_vector_type(8)));

__device__ __forceinline__ unsigned short f2bf(float x) {
    unsigned u = __float_as_uint(x);
    u += 0x7FFFu + ((u >> 16) & 1u);   // RNE
    return (unsigned short)(u >> 16);
}

// float -> orderable uint (monotone), so atomicMax(uint) == float max
__device__ __forceinline__ unsigned enc_f32(float f) {
    unsigned u = __float_as_uint(f);
    return (u & 0x80000000u) ? ~u : (u | 0x80000000u);
}
__device__ __forceinline__ float dec_f32(unsigned e) {
    return __uint_as_float((e & 0x80000000u) ? (e ^ 0x80000000u) : ~e);
}

// ---------- normalize rows of z and P to bf16, init atomic cells ----------
__global__ __launch_bounds__(256) void k_prep(
        const float* __restrict__ z, const float* __restrict__ P,
        unsigned short* __restrict__ zb, unsigned short* __restrict__ pb,
        unsigned* __restrict__ posU, unsigned* __restrict__ negU) {
    const int b = blockIdx.x;
    const int t = threadIdx.x;
    if (b < BATCH && t == 0) {
        posU[b] = enc_f32(-INFINITY);
        negU[b] = enc_f32(-INFINITY);
    }
    const float* src = nullptr;
    unsigned short* dst;
    if (b < BATCH) {
        src = z + (size_t)b * D;
        dst = zb + (size_t)b * D;
    } else {
        const int r = b - BATCH;
        dst = pb + (size_t)r * D;
        if (r < NPROTO) src = P + (size_t)r * D;
    }
    if (src == nullptr) {                 // padded proto row -> zeros
        ushort4 zr = make_ushort4(0, 0, 0, 0);
        ((ushort4*)dst)[t] = zr;
        return;
    }
    float4 v = ((const float4*)src)[t];   // 256 threads * 4 floats = 1024
    float ss = v.x * v.x + v.y * v.y + v.z * v.z + v.w * v.w;
    #pragma unroll
    for (int off = 32; off >= 1; off >>= 1) ss += __shfl_xor(ss, off);
    __shared__ float red[4];
    const int wave = t >> 6;
    if ((t & 63) == 0) red[wave] = ss;
    __syncthreads();
    const float s = red[0] + red[1] + red[2] + red[3];
    const float inv = 1.0f / fmaxf(sqrtf(s), 1e-12f);
    ushort4 o;
    o.x = f2bf(v.x * inv); o.y = f2bf(v.y * inv);
    o.z = f2bf(v.z * inv); o.w = f2bf(v.w * inv);
    ((ushort4*)dst)[t] = o;
}

// async global->LDS, 16B per lane, dest = wave-uniform base + lane*16
#define GLL(gp, lp) __builtin_amdgcn_global_load_lds( \
    (__attribute__((address_space(1))) const unsigned int*)(const void*)(gp), \
    (__attribute__((address_space(3))) unsigned int*)(void*)(lp), 16, 0, 0)

// ---------- 128x128 bf16 MFMA GEMM tile + fused masked row-max ----------
__global__ __launch_bounds__(256) void k_gemm(
        const unsigned short* __restrict__ zb,
        const unsigned short* __restrict__ pb,
        const int* __restrict__ y,
        unsigned* __restrict__ posU, unsigned* __restrict__ negU) {
    __shared__ unsigned short As[128 * 32];   // [row][k] 8 KB
    __shared__ unsigned short Bs[128 * 32];   // [proto][k] 8 KB

    const int bx = blockIdx.x;            // proto tile 0..39
    const int by = blockIdx.y;            // batch-row tile 0..127
    const int t = threadIdx.x;
    const int lane = t & 63;
    const int wave = t >> 6;
    const int wm = wave >> 1, wn = wave & 1;   // 2x2 waves of 64x64
    const int lm = lane & 15, lk = lane >> 4;

    const int rowbase = by * 128;
    const int colbase = bx * 128;

    // staging: thread t handles 16B chunk -> LDS element t*8 (linear),
    // covering tile row t>>2, k-offset (t&3)*8; second pass = row+64
    const int r0 = t >> 2;
    const int kk0 = (t & 3) * 8;

    const unsigned short* gA  = zb + (size_t)(rowbase + r0) * D + kk0;
    const unsigned short* gA2 = gA + (size_t)64 * D;
    const unsigned short* gB  = pb + (size_t)(colbase + r0) * D + kk0;
    const unsigned short* gB2 = gB + (size_t)64 * D;

    unsigned short* lA0 = As + wave * 512;          // wave-uniform bases
    unsigned short* lA1 = As + 2048 + wave * 512;
    unsigned short* lB0 = Bs + wave * 512;
    unsigned short* lB1 = Bs + 2048 + wave * 512;

    f32x4 acc[4][4];
    #pragma unroll
    for (int i = 0; i < 4; ++i)
        #pragma unroll
        for (int j = 0; j < 4; ++j) {
            f32x4 z4 = {0.0f, 0.0f, 0.0f, 0.0f};
            acc[i][j] = z4;
        }

    const int aoff = (wm * 64 + lm) * 32 + lk * 8;
    const int boff = (wn * 64 + lm) * 32 + lk * 8;

    for (int kt = 0; kt < 32; ++kt) {
        const int ko = kt * 32;
        GLL(gA + ko, lA0);
        GLL(gA2 + ko, lA1);
        GLL(gB + ko, lB0);
        GLL(gB2 + ko, lB1);
        __syncthreads();

        bf16x8 a[4], b[4];
        #pragma unroll
        for (int mi = 0; mi < 4; ++mi)
            a[mi] = *(const bf16x8*)(As + aoff + mi * 16 * 32);
        #pragma unroll
        for (int ni = 0; ni < 4; ++ni)
            b[ni] = *(const bf16x8*)(Bs + boff + ni * 16 * 32);
        #pragma unroll
        for (int mi = 0; mi < 4; ++mi)
            #pragma unroll
            for (int ni = 0; ni < 4; ++ni)
                acc[mi][ni] = __builtin_amdgcn_mfma_f32_16x16x32_bf16(
                    a[mi], b[ni], acc[mi][ni], 0, 0, 0);
        __syncthreads();
    }

    // fused epilogue: masked pos/neg max per output row
    // C/D layout: col = lane&15, row = (lane>>4)*4 + reg  (m89-verified)
    const int col0 = colbase + wn * 64 + lm;
    #pragma unroll
    for (int mi = 0; mi < 4; ++mi) {
        #pragma unroll
        for (int r = 0; r < 4; ++r) {
            const int row_g = rowbase + wm * 64 + mi * 16 + lk * 4 + r;
            const int yv = y[row_g];
            float pm = -INFINITY, nm = -INFINITY;
            #pragma unroll
            for (int ni = 0; ni < 4; ++ni) {
                const int col_g = col0 + ni * 16;
                const float v = acc[mi][ni][r];
                const bool same = (col_g / 5) == yv;      // same => col_g < 5000
                if (same) pm = fmaxf(pm, v);
                else if (col_g < NPROTO) nm = fmaxf(nm, v);
            }
            #pragma unroll
            for (int off = 1; off < 16; off <<= 1) {
                pm = fmaxf(pm, __shfl_xor(pm, off));
                nm = fmaxf(nm, __shfl_xor(nm, off));
            }
            if (lm == 0) {
                if (pm > -INFINITY) atomicMax(&posU[row_g], enc_f32(pm));
                if (nm > -INFINITY) atomicMax(&negU[row_g], enc_f32(nm));
            }
        }
    }
}

// ---------- decode to output ----------
__global__ __launch_bounds__(256) void k_finish(
        const unsigned* __restrict__ posU, const unsigned* __restrict__ negU,
        float* __restrict__ out) {
    const int i = blockIdx.x * 256 + threadIdx.x;
    if (i < BATCH) {
        out[i] = dec_f32(posU[i]);
        out[BATCH + i] = dec_f32(negU[i]);
    }
}

extern "C" void kernel_launch(void* const* d_in, const int* in_sizes, int n_in,
                              void* d_out, int out_size, void* d_ws, size_t ws_size,
                              hipStream_t stream) {
    const float* z = (const float*)d_in[0];
    const int*   y = (const int*)d_in[1];
    const float* P = (const float*)d_in[2];

    // ws layout: zb 32MB | pb 10MB | posU 64KB | negU 64KB  (~42.2 MB)
    unsigned short* zb = (unsigned short*)d_ws;
    unsigned short* pb = zb + (size_t)BATCH * D;
    unsigned* posU = (unsigned*)(pb + (size_t)NPROTO_PAD * D);
    unsigned* negU = posU + BATCH;
    float* out = (float*)d_out;

    k_prep<<<BATCH + NPROTO_PAD, 256, 0, stream>>>(z, P, zb, pb, posU, negU);
    dim3 grid(NTILE_N, NTILE_M);
    k_gemm<<<grid, 256, 0, stream>>>(zb, pb, y, posU, negU);
    k_finish<<<BATCH / 256, 256, 0, stream>>>(posU, negU, out);
}